// Round 8
// baseline (169.860 us; speedup 1.0000x reference)
//
#include <hip/hip_runtime.h>
#include <hip/hip_bf16.h>

// Sparse conv gather->GEMM->scatter for MI355X (gfx950), atomic-light design:
//   kA : KOFF x NCHUNK rank-blocks (each scans one k-slab, claims rows in its
//        8192-row chunk via LDS nibble counters -> sparse slot table
//        [row][27][4] uint16) + cast-blocks (f32 -> bf16 features)
//   k2 : PURE per-offset MFMA GEMM, bf16 gather, depth-4 register pipeline
//        -> vals[pair][64] bf16 (permuted channel layout, 2x16B stores/lane)
//   k3 : per-row slot-scan + ballot compaction + 4-deep segmented reduce -> out
//   k4 : tiny fixup applying rank-overflow pairs (~500) with f32 atomics
// Fallback to a pure-atomic kernel for exotic shapes / tiny ws.

typedef __bf16 bf16x8 __attribute__((ext_vector_type(8)));
typedef float f32x4 __attribute__((ext_vector_type(4)));

#define KOFF 27
#define SLOTK 4                 // slots per (row,k) cell
#define NSLOT (KOFF * SLOTK)    // 108 entries per row
#define OVFCAP 8192             // overflow list capacity (E[ovf] ~ 505)
#define WPAD 72                 // LDS pad for W tile
#define ROWCHUNK 8192           // rows per rank-block chunk
#define NIBW (ROWCHUNK / 8)     // 1024 words of 8 nibbles = 4 KB LDS

// ---- kA: chunked rank-builder + f32->bf16 cast ----
__global__ __launch_bounds__(256) void kA_rank_cast(
    const float* __restrict__ feat, const int* __restrict__ nout,
    __bf16* __restrict__ fb, unsigned short* __restrict__ slots,
    int2* __restrict__ ovf, int* __restrict__ ovfcnt, int Lpairs, int nElems,
    int nchunk, int rankBlocks) {
  __shared__ unsigned int nib[NIBW];
  if ((int)blockIdx.x < rankBlocks) {
    const int k = blockIdx.x / nchunk;
    const int chunk = blockIdx.x % nchunk;
    const int lo = chunk * ROWCHUNK;
    const int tid = threadIdx.x;
    for (int i = tid; i < NIBW; i += 256) nib[i] = 0u;
    __syncthreads();
    const int* nk = nout + k * Lpairs;
    for (int base = 0; base < Lpairs; base += 2048) {
      int l[8], row[8];
#pragma unroll
      for (int j = 0; j < 8; ++j) {
        l[j] = base + j * 256 + tid;
        row[j] = (l[j] < Lpairs) ? nk[l[j]] : -1;
      }
#pragma unroll
      for (int j = 0; j < 8; ++j) {
        int rr = row[j] - lo;
        if (rr >= 0 && rr < ROWCHUNK) {
          unsigned int sh = ((unsigned)rr & 7u) * 4u;
          unsigned int old = atomicAdd(&nib[rr >> 3], 1u << sh);
          int rank = (old >> sh) & 15;
          if (rank < SLOTK) {
            slots[(size_t)row[j] * NSLOT + k * SLOTK + rank] =
                (unsigned short)l[j];
          } else {
            int idx = atomicAdd(ovfcnt, 1);
            if (idx < OVFCAP) ovf[idx] = make_int2(row[j], k * Lpairs + l[j]);
          }
        }
      }
    }
  } else {
    int i = ((blockIdx.x - rankBlocks) * 256 + threadIdx.x) * 8;
    if (i < nElems) {
      f32x4 a = *(const f32x4*)(feat + i);
      f32x4 b = *(const f32x4*)(feat + i + 4);
      bf16x8 v;
#pragma unroll
      for (int j = 0; j < 4; ++j) {
        v[j] = (__bf16)a[j];
        v[j + 4] = (__bf16)b[j];
      }
      *(bf16x8*)(fb + i) = v;
    }
  }
}

// ---- k2: PURE GEMM (depth-4 pipeline) ----
// Swapped-operand mfma: D[ch][pair]; lane (g,r) owns pair base+r.
// vals channel layout: c' = g*16 + t*4 + reg (lane's 16 ch contiguous).
template <int ITER>
__global__ __launch_bounds__(256) void k2_gemm(
    const __bf16* __restrict__ fb, const float* __restrict__ kern,
    const int* __restrict__ nin, __bf16* __restrict__ vals, int Lpairs,
    int blocksPerK) {
  __shared__ __bf16 ldsBT[64 * WPAD];  // ldsBT[c*WPAD+i] = W[i][c]
  const int bk = blockIdx.x / blocksPerK;
  const int chunk = blockIdx.x % blocksPerK;
  const float* kb = kern + bk * 4096;
  for (int idx = threadIdx.x; idx < 4096; idx += 256) {
    int i = idx >> 6, c = idx & 63;
    ldsBT[c * WPAD + i] = (__bf16)kb[idx];
  }
  __syncthreads();

  const int lane = threadIdx.x & 63;
  const int wave = threadIdx.x >> 6;
  const int r = lane & 15, g = lane >> 4;

  bf16x8 wfrag[2][4];
#pragma unroll
  for (int s = 0; s < 2; ++s)
#pragma unroll
    for (int t = 0; t < 4; ++t)
      wfrag[s][t] = *(const bf16x8*)&ldsBT[(t * 16 + r) * WPAD + g * 8 + s * 32];

  const int* ninK = nin + bk * Lpairs;
  const int base0 = chunk * (4 * ITER * 16) + wave * (ITER * 16);
  const int MAXB = Lpairs - 16;  // Lpairs % 16 == 0

  // Clamped tile base: out-of-range tiles recompute the last tile
  // (idempotent duplicate stores of identical values).
#define PB(IT) (((base0 + (IT) * 16) < MAXB) ? (base0 + (IT) * 16) : MAXB)

  int rows[ITER];
#pragma unroll
  for (int it = 0; it < ITER; ++it) rows[it] = ninK[PB(it) + r];

  // Feature pipeline: depth 4 (3 buffered + 1 issuing) -> 8 loads in flight.
  bf16x8 A0[4], A1[4];
#pragma unroll
  for (int d = 0; d < 3; ++d) {
    const __bf16* ap = fb + (size_t)rows[d] * 64 + g * 8;
    A0[d] = *(const bf16x8*)(ap);
    A1[d] = *(const bf16x8*)(ap + 32);
  }

#pragma unroll
  for (int it = 0; it < ITER; ++it) {
    if (it + 3 < ITER) {
      const __bf16* ap = fb + (size_t)rows[it + 3] * 64 + g * 8;
      A0[(it + 3) & 3] = *(const bf16x8*)(ap);
      A1[(it + 3) & 3] = *(const bf16x8*)(ap + 32);
    }

    f32x4 acc[4] = {f32x4{0.f, 0.f, 0.f, 0.f}, f32x4{0.f, 0.f, 0.f, 0.f},
                    f32x4{0.f, 0.f, 0.f, 0.f}, f32x4{0.f, 0.f, 0.f, 0.f}};
#pragma unroll
    for (int t = 0; t < 4; ++t) {
      acc[t] = __builtin_amdgcn_mfma_f32_16x16x32_bf16(wfrag[0][t], A0[it & 3], acc[t], 0, 0, 0);
      acc[t] = __builtin_amdgcn_mfma_f32_16x16x32_bf16(wfrag[1][t], A1[it & 3], acc[t], 0, 0, 0);
    }

    __bf16* vp = vals + ((size_t)bk * Lpairs + PB(it) + r) * 64 + g * 16;
    bf16x8 v0, v1;
#pragma unroll
    for (int reg = 0; reg < 4; ++reg) {
      v0[reg] = (__bf16)acc[0][reg];
      v0[reg + 4] = (__bf16)acc[1][reg];
      v1[reg] = (__bf16)acc[2][reg];
      v1[reg + 4] = (__bf16)acc[3][reg];
    }
    *(bf16x8*)vp = v0;
    *(bf16x8*)(vp + 8) = v1;
  }
#undef PB
}

// ---- k3: slot-scan + compact + 4-deep reduce ----
__global__ __launch_bounds__(256) void k3_reduce(
    const __bf16* __restrict__ vals, const unsigned int* __restrict__ slots32,
    float* __restrict__ out, int Nrows, int Lpairs) {
  __shared__ int list[4][64];
  const int w = threadIdx.x >> 6;
  const int lane = threadIdx.x & 63;
  int row = blockIdx.x * 4 + w;
  if (row >= Nrows) row = Nrows - 1;  // duplicate-process last row (benign)

  // 108 uint16 entries = 54 dwords; lane < 54 loads one dword (2 entries).
  unsigned int wv = 0xFFFFFFFFu;
  if (lane < NSLOT / 2) wv = slots32[(size_t)row * (NSLOT / 2) + lane];
  const int e0 = wv & 0xFFFF;
  const int e1 = (int)(wv >> 16);
  const bool v0 = (lane < NSLOT / 2) && (e0 != 0xFFFF);
  const bool v1 = (lane < NSLOT / 2) && (e1 != 0xFFFF);
  const int k = lane >> 1;  // entry j=2*lane and j=2*lane+1 share k = j>>2
  const int p0 = k * Lpairs + e0;
  const int p1 = k * Lpairs + e1;

  unsigned long long m0 = __ballot(v0);
  unsigned long long m1 = __ballot(v1);
  unsigned long long below = ((unsigned long long)1 << lane) - 1ull;
  int c0 = __popcll(m0);
  int cnt = c0 + __popcll(m1);
  int pos0 = __popcll(m0 & below);
  int pos1 = c0 + __popcll(m1 & below);
  if (cnt > 64) cnt = 64;
  if (v0 && pos0 < 64) list[w][pos0] = p0;
  if (v1 && pos1 < 64) list[w][pos1] = p1;
  __syncthreads();

  // out channel c=lane lives at vals offset c' = ((c>>2)&3)*16 + (c>>4)*4 + (c&3)
  const int cp = ((lane >> 2) & 3) * 16 + (lane >> 4) * 4 + (lane & 3);
  float acc = 0.f;
  int j = 0;
  for (; j + 3 < cnt; j += 4) {
    int s0 = list[w][j], s1 = list[w][j + 1], s2 = list[w][j + 2], s3 = list[w][j + 3];
    float q0 = (float)vals[(size_t)s0 * 64 + cp];
    float q1 = (float)vals[(size_t)s1 * 64 + cp];
    float q2 = (float)vals[(size_t)s2 * 64 + cp];
    float q3 = (float)vals[(size_t)s3 * 64 + cp];
    acc += q0; acc += q1; acc += q2; acc += q3;
  }
  for (; j < cnt; ++j) acc += (float)vals[(size_t)list[w][j] * 64 + cp];
  out[(size_t)row * 64 + lane] = acc;
}

// ---- k4: overflow fixup (~500 pairs) ----
__global__ __launch_bounds__(256) void k4_fixup(const __bf16* __restrict__ vals,
                                                const int2* __restrict__ ovf,
                                                const int* __restrict__ ovfcnt,
                                                float* __restrict__ out) {
  int gid = blockIdx.x * 256 + threadIdx.x;
  int i = gid >> 6, lane = gid & 63;
  int n = *ovfcnt;
  if (n > OVFCAP) n = OVFCAP;
  if (i >= n) return;
  int row = ovf[i].x, pid = ovf[i].y;
  const int cp = ((lane >> 2) & 3) * 16 + (lane >> 4) * 4 + (lane & 3);
  atomicAdd(&out[(size_t)row * 64 + lane], (float)vals[(size_t)pid * 64 + cp]);
}

// ---- Fallback: atomic kernel (exotic shapes / tiny ws) ----
template <int ITER>
__global__ __launch_bounds__(256) void spconv_atomic_kernel(
    const float* __restrict__ feat, const float* __restrict__ kern,
    const int* __restrict__ nin, const int* __restrict__ nout,
    float* __restrict__ out, int Lpairs, int blocksPerK) {
  __shared__ __bf16 ldsBT[64 * WPAD];
  const int bk = blockIdx.x / blocksPerK;
  const int chunk = blockIdx.x % blocksPerK;
  const float* kb = kern + bk * 4096;
  for (int idx = threadIdx.x; idx < 4096; idx += 256) {
    int i = idx >> 6, c = idx & 63;
    ldsBT[c * WPAD + i] = (__bf16)kb[idx];
  }
  __syncthreads();
  const int lane = threadIdx.x & 63;
  const int wave = threadIdx.x >> 6;
  const int r = lane & 15, g = lane >> 4;
  bf16x8 bfrag[2][4];
#pragma unroll
  for (int s = 0; s < 2; ++s)
#pragma unroll
    for (int t = 0; t < 4; ++t)
      bfrag[s][t] = *(const bf16x8*)&ldsBT[(t * 16 + r) * WPAD + g * 8 + s * 32];
  const int* ninK = nin + bk * Lpairs;
  const int* noutK = nout + bk * Lpairs;
  const int base0 = chunk * (4 * ITER * 16) + wave * (ITER * 16);
  for (int it = 0; it < ITER; ++it) {
    const int base = base0 + it * 16;
    if (base >= Lpairs) break;
    const int arow = ninK[base + r];
    const float* ap = feat + (size_t)arow * 64 + g * 8;
    f32x4 f0 = *(const f32x4*)(ap);
    f32x4 f1 = *(const f32x4*)(ap + 4);
    f32x4 f2 = *(const f32x4*)(ap + 32);
    f32x4 f3 = *(const f32x4*)(ap + 36);
    bf16x8 a0, a1;
#pragma unroll
    for (int j = 0; j < 4; ++j) {
      a0[j] = (__bf16)f0[j];
      a0[j + 4] = (__bf16)f1[j];
      a1[j] = (__bf16)f2[j];
      a1[j + 4] = (__bf16)f3[j];
    }
    f32x4 acc[4] = {f32x4{0.f, 0.f, 0.f, 0.f}, f32x4{0.f, 0.f, 0.f, 0.f},
                    f32x4{0.f, 0.f, 0.f, 0.f}, f32x4{0.f, 0.f, 0.f, 0.f}};
#pragma unroll
    for (int t = 0; t < 4; ++t) {
      acc[t] = __builtin_amdgcn_mfma_f32_16x16x32_bf16(a0, bfrag[0][t], acc[t], 0, 0, 0);
      acc[t] = __builtin_amdgcn_mfma_f32_16x16x32_bf16(a1, bfrag[1][t], acc[t], 0, 0, 0);
    }
    int orow[4];
#pragma unroll
    for (int reg = 0; reg < 4; ++reg) orow[reg] = noutK[base + g * 4 + reg];
#pragma unroll
    for (int t = 0; t < 4; ++t)
#pragma unroll
      for (int reg = 0; reg < 4; ++reg)
        atomicAdd(out + (size_t)orow[reg] * 64 + t * 16 + r, acc[t][reg]);
  }
}

extern "C" void kernel_launch(void* const* d_in, const int* in_sizes, int n_in,
                              void* d_out, int out_size, void* d_ws, size_t ws_size,
                              hipStream_t stream) {
  const float* feat = (const float*)d_in[0];
  const float* kern = (const float*)d_in[1];
  const int* nin = (const int*)d_in[2];
  const int* nout = (const int*)d_in[3];
  float* out = (float*)d_out;

  const int total = in_sizes[2];        // 27*L pairs
  const int Lpairs = total / KOFF;      // 50000
  const int Nrows = out_size / 64;      // 100000
  const int nElems = Nrows * 64;

  constexpr int ITER = 8;
  const int pairsPerBlock = 4 * ITER * 16;  // 512
  const int blocksPerK = (Lpairs + pairsPerBlock - 1) / pairsPerBlock;

  // ws layout: slots (uint16, 0xFF-init) | ovf | ovfcnt | vals
  const size_t slotsBytes = (size_t)Nrows * NSLOT * 2;
  const size_t ovfOff = (slotsBytes + 255) & ~(size_t)255;
  const size_t cntOff = (ovfOff + (size_t)OVFCAP * 8 + 255) & ~(size_t)255;
  const size_t valsOff = (cntOff + 256 + 255) & ~(size_t)255;
  const size_t needed = valsOff + (size_t)total * 64 * 2;

  const bool shapeOK = (Lpairs <= 65535) && (Lpairs % 16 == 0) &&
                       (total % KOFF == 0);

  if (shapeOK && ws_size >= needed) {
    unsigned short* slots = (unsigned short*)d_ws;
    int2* ovf = (int2*)((char*)d_ws + ovfOff);
    int* ovfcnt = (int*)((char*)d_ws + cntOff);
    __bf16* vals = (__bf16*)((char*)d_ws + valsOff);
    __bf16* fb = (__bf16*)d_out;  // 12.8 MB scratch inside 25.6 MB out buffer

    hipMemsetAsync(slots, 0xFF, slotsBytes, stream);
    hipMemsetAsync(ovfcnt, 0, 4, stream);

    const int nchunk = (Nrows + ROWCHUNK - 1) / ROWCHUNK;
    const int rankBlocks = KOFF * nchunk;
    const int castBlocks = (nElems / 8 + 255) / 256;
    kA_rank_cast<<<rankBlocks + castBlocks, 256, 0, stream>>>(
        feat, nout, fb, slots, ovf, ovfcnt, Lpairs, nElems, nchunk, rankBlocks);
    k2_gemm<ITER><<<KOFF * blocksPerK, 256, 0, stream>>>(fb, kern, nin, vals,
                                                         Lpairs, blocksPerK);
    k3_reduce<<<(Nrows + 3) / 4, 256, 0, stream>>>(
        vals, (const unsigned int*)slots, out, Nrows, Lpairs);
    k4_fixup<<<OVFCAP * 64 / 256, 256, 0, stream>>>(vals, ovf, ovfcnt, out);
  } else {
    hipMemsetAsync(d_out, 0, (size_t)out_size * sizeof(float), stream);
    spconv_atomic_kernel<ITER><<<KOFF * blocksPerK, 256, 0, stream>>>(
        feat, kern, nin, nout, out, Lpairs, blocksPerK);
  }
}

// Round 9
// 162.453 us; speedup vs baseline: 1.0456x; 1.0456x over previous
//
#include <hip/hip_runtime.h>
#include <hip/hip_bf16.h>

// Sparse conv for MI355X (gfx950), fused output-stationary design:
//   kA : rank-blocks (LDS nibble counters -> sparse slot table [row][27][4] u16)
//        + cast-blocks (f32 -> bf16 feature table in ws)
//   kF : fused kernel. Wave owns 16 output rows; accumulator D[64ch][16rows]
//        lives in registers across all 27 offsets. Per k: read slot cell,
//        gather+sum features (linearity: sum-before-GEMM), 8 MFMAs vs W[k]
//        staged in double-buffered LDS. Out written once. NO vals round-trip.
//   k4 : overflow fixup (~500 pairs) recomputes feat.W directly, atomicAdd.
// Fallback to a pure-atomic kernel for exotic shapes / tiny ws.

typedef __bf16 bf16x8 __attribute__((ext_vector_type(8)));
typedef float f32x4 __attribute__((ext_vector_type(4)));

#define KOFF 27
#define SLOTK 4                 // slots per (row,k) cell
#define NSLOT (KOFF * SLOTK)    // 108 entries per row
#define OVFCAP 8192             // overflow list capacity (E[ovf] ~ 505)
#define WPAD 72                 // LDS pad for W tile
#define ROWCHUNK 8192           // rows per rank-block chunk
#define NIBW (ROWCHUNK / 8)     // 4 KB LDS nibble counters

// ---- kA: chunked rank-builder + f32->bf16 cast ----
__global__ __launch_bounds__(256) void kA_rank_cast(
    const float* __restrict__ feat, const int* __restrict__ nout,
    __bf16* __restrict__ fb, unsigned short* __restrict__ slots,
    int2* __restrict__ ovf, int* __restrict__ ovfcnt, int Lpairs, int nElems,
    int nchunk, int rankBlocks) {
  __shared__ unsigned int nib[NIBW];
  if ((int)blockIdx.x < rankBlocks) {
    const int k = blockIdx.x / nchunk;
    const int chunk = blockIdx.x % nchunk;
    const int lo = chunk * ROWCHUNK;
    const int tid = threadIdx.x;
    for (int i = tid; i < NIBW; i += 256) nib[i] = 0u;
    __syncthreads();
    const int* nk = nout + k * Lpairs;
    for (int base = 0; base < Lpairs; base += 2048) {
      int l[8], row[8];
#pragma unroll
      for (int j = 0; j < 8; ++j) {
        l[j] = base + j * 256 + tid;
        row[j] = (l[j] < Lpairs) ? nk[l[j]] : -1;
      }
#pragma unroll
      for (int j = 0; j < 8; ++j) {
        int rr = row[j] - lo;
        if (rr >= 0 && rr < ROWCHUNK) {
          unsigned int sh = ((unsigned)rr & 7u) * 4u;
          unsigned int old = atomicAdd(&nib[rr >> 3], 1u << sh);
          int rank = (old >> sh) & 15;
          if (rank < SLOTK) {
            slots[(size_t)row[j] * NSLOT + k * SLOTK + rank] =
                (unsigned short)l[j];
          } else {
            int idx = atomicAdd(ovfcnt, 1);
            if (idx < OVFCAP) ovf[idx] = make_int2(row[j], k * Lpairs + l[j]);
          }
        }
      }
    }
  } else {
    int i = ((blockIdx.x - rankBlocks) * 256 + threadIdx.x) * 8;
    if (i < nElems) {
      f32x4 a = *(const f32x4*)(feat + i);
      f32x4 b = *(const f32x4*)(feat + i + 4);
      bf16x8 v;
#pragma unroll
      for (int j = 0; j < 4; ++j) {
        v[j] = (__bf16)a[j];
        v[j + 4] = (__bf16)b[j];
      }
      *(bf16x8*)(fb + i) = v;
    }
  }
}

// ---- kF: fused output-stationary GEMM ----
// Wave handles rows rowbase..rowbase+15. Lane (g = lane>>4, r = lane&15):
//   B operand per k: summed cell features of row (rowbase+r),
//     channels [g*8..g*8+7] (b0) and [32+g*8..] (b1)  [proven k2 mapping]
//   A operand: W[k]^T from LDS (proven wfrag layout)
//   D: col=r -> row, row=g*4+reg (+t*16) -> channel; held in regs across k.
__global__ __launch_bounds__(256) void kF_fused(
    const __bf16* __restrict__ fb, const float* __restrict__ kern,
    const int* __restrict__ nin, const unsigned short* __restrict__ slots,
    float* __restrict__ out, int Lpairs, int Nrows) {
  __shared__ __bf16 ldsW[2][64 * WPAD];
  const int tid = threadIdx.x;
  const int wv = tid >> 6, lane = tid & 63;
  const int r = lane & 15, g = lane >> 4;
  int row = blockIdx.x * 64 + wv * 16 + r;
  if (row >= Nrows) row = Nrows - 1;  // duplicate rows write identical values
  const unsigned short* srow = slots + (size_t)row * NSLOT;

  // stage W[0] (256 threads x 16 elems, transposed bf16 into LDS)
  {
    const int i = tid >> 2;           // input channel 0..63
    const int c0 = (tid & 3) * 16;    // output-channel base
    const float* kb = kern;
    f32x4 wa = *(const f32x4*)(kb + i * 64 + c0);
    f32x4 wb = *(const f32x4*)(kb + i * 64 + c0 + 4);
    f32x4 wc = *(const f32x4*)(kb + i * 64 + c0 + 8);
    f32x4 wd = *(const f32x4*)(kb + i * 64 + c0 + 12);
#pragma unroll
    for (int q = 0; q < 4; ++q) {
      ldsW[0][(c0 + q) * WPAD + i] = (__bf16)wa[q];
      ldsW[0][(c0 + 4 + q) * WPAD + i] = (__bf16)wb[q];
      ldsW[0][(c0 + 8 + q) * WPAD + i] = (__bf16)wc[q];
      ldsW[0][(c0 + 12 + q) * WPAD + i] = (__bf16)wd[q];
    }
  }

  // Index pipeline prologue: slot entries for k=0,1; nin rows for k=0.
  uint2 sv0 = *(const uint2*)(srow);
  uint2 sv1 = *(const uint2*)(srow + SLOTK);
  int e[4] = {(int)(sv0.x & 0xFFFF), (int)(sv0.x >> 16),
              (int)(sv0.y & 0xFFFF), (int)(sv0.y >> 16)};
  int en[4] = {(int)(sv1.x & 0xFFFF), (int)(sv1.x >> 16),
               (int)(sv1.y & 0xFFFF), (int)(sv1.y >> 16)};
  int irow[4], irown[4];
#pragma unroll
  for (int j = 0; j < 4; ++j) irow[j] = (e[j] != 0xFFFF) ? nin[e[j]] : -1;

  f32x4 acc[4] = {f32x4{0.f, 0.f, 0.f, 0.f}, f32x4{0.f, 0.f, 0.f, 0.f},
                  f32x4{0.f, 0.f, 0.f, 0.f}, f32x4{0.f, 0.f, 0.f, 0.f}};
  __syncthreads();

  for (int k = 0; k < KOFF; ++k) {
    const int kb = k & 1;
    // (1) gather loads for k (indices ready) -- up to 8 independent 16B loads
    bf16x8 fa[4], fc[4];
#pragma unroll
    for (int j = 0; j < 4; ++j) {
      if (irow[j] >= 0) {
        const __bf16* ap = fb + (size_t)irow[j] * 64 + g * 8;
        fa[j] = *(const bf16x8*)(ap);
        fc[j] = *(const bf16x8*)(ap + 32);
      }
    }
    // (2) nin loads for k+1 (entries ready)
    const int* ninK1 = nin + (k + 1) * Lpairs;
#pragma unroll
    for (int j = 0; j < 4; ++j)
      irown[j] = (k + 1 < KOFF && en[j] != 0xFFFF) ? ninK1[en[j]] : -1;
    // (3) slot entries for k+2
    uint2 sv2 = make_uint2(0xFFFFFFFFu, 0xFFFFFFFFu);
    if (k + 2 < KOFF) sv2 = *(const uint2*)(srow + (k + 2) * SLOTK);
    // (4) stage W[k+1] into the other LDS buffer
    if (k + 1 < KOFF) {
      const int i = tid >> 2;
      const int c0 = (tid & 3) * 16;
      const float* kbp = kern + (k + 1) * 4096;
      f32x4 wa = *(const f32x4*)(kbp + i * 64 + c0);
      f32x4 wb = *(const f32x4*)(kbp + i * 64 + c0 + 4);
      f32x4 wc = *(const f32x4*)(kbp + i * 64 + c0 + 8);
      f32x4 wd = *(const f32x4*)(kbp + i * 64 + c0 + 12);
#pragma unroll
      for (int q = 0; q < 4; ++q) {
        ldsW[kb ^ 1][(c0 + q) * WPAD + i] = (__bf16)wa[q];
        ldsW[kb ^ 1][(c0 + 4 + q) * WPAD + i] = (__bf16)wb[q];
        ldsW[kb ^ 1][(c0 + 8 + q) * WPAD + i] = (__bf16)wc[q];
        ldsW[kb ^ 1][(c0 + 12 + q) * WPAD + i] = (__bf16)wd[q];
      }
    }
    // (5) cell pre-sum in f32 (linearity: sum before GEMM)
    float s0[8] = {0.f, 0.f, 0.f, 0.f, 0.f, 0.f, 0.f, 0.f};
    float s1[8] = {0.f, 0.f, 0.f, 0.f, 0.f, 0.f, 0.f, 0.f};
#pragma unroll
    for (int j = 0; j < 4; ++j) {
      if (irow[j] >= 0) {
#pragma unroll
        for (int q = 0; q < 8; ++q) {
          s0[q] += (float)fa[j][q];
          s1[q] += (float)fc[j][q];
        }
      }
    }
    bf16x8 b0, b1;
#pragma unroll
    for (int q = 0; q < 8; ++q) {
      b0[q] = (__bf16)s0[q];
      b1[q] = (__bf16)s1[q];
    }
    // (6) W fragments from LDS + 8 MFMAs accumulating into persistent acc
    bf16x8 w0f[4], w1f[4];
#pragma unroll
    for (int t = 0; t < 4; ++t) {
      w0f[t] = *(const bf16x8*)&ldsW[kb][(t * 16 + r) * WPAD + g * 8];
      w1f[t] = *(const bf16x8*)&ldsW[kb][(t * 16 + r) * WPAD + g * 8 + 32];
    }
#pragma unroll
    for (int t = 0; t < 4; ++t) {
      acc[t] = __builtin_amdgcn_mfma_f32_16x16x32_bf16(w0f[t], b0, acc[t], 0, 0, 0);
      acc[t] = __builtin_amdgcn_mfma_f32_16x16x32_bf16(w1f[t], b1, acc[t], 0, 0, 0);
    }
    __syncthreads();
    // rotate index pipeline
#pragma unroll
    for (int j = 0; j < 4; ++j) irow[j] = irown[j];
    en[0] = (int)(sv2.x & 0xFFFF);
    en[1] = (int)(sv2.x >> 16);
    en[2] = (int)(sv2.y & 0xFFFF);
    en[3] = (int)(sv2.y >> 16);
  }

  // Epilogue: lane (g,r) holds channels t*16+g*4+{0..3} of row.
  float* op = out + (size_t)row * 64;
#pragma unroll
  for (int t = 0; t < 4; ++t) *(f32x4*)(op + t * 16 + g * 4) = acc[t];
}

// ---- k4: overflow fixup (~500 pairs): recompute feat.W, atomicAdd ----
__global__ __launch_bounds__(256) void k4_fixup(
    const __bf16* __restrict__ fb, const float* __restrict__ kern,
    const int* __restrict__ nin, const int2* __restrict__ ovf,
    const int* __restrict__ ovfcnt, float* __restrict__ out, int Lpairs) {
  int gid = blockIdx.x * 256 + threadIdx.x;
  int i = gid >> 6, c = gid & 63;
  int n = *ovfcnt;
  if (n > OVFCAP) n = OVFCAP;
  if (i >= n) return;
  int row = ovf[i].x, pid = ovf[i].y;
  int k = pid / Lpairs;
  int irow = nin[pid];
  const float* wk = kern + k * 4096 + c;
  const __bf16* f = fb + (size_t)irow * 64;
  float s = 0.f;
#pragma unroll 8
  for (int q = 0; q < 64; ++q) s += (float)f[q] * wk[q * 64];
  atomicAdd(&out[(size_t)row * 64 + c], s);
}

// ---- Fallback: atomic kernel (exotic shapes / tiny ws) ----
__global__ __launch_bounds__(256) void spconv_atomic_kernel(
    const float* __restrict__ feat, const float* __restrict__ kern,
    const int* __restrict__ nin, const int* __restrict__ nout,
    float* __restrict__ out, int Lpairs, int blocksPerK) {
  __shared__ __bf16 ldsBT[64 * WPAD];
  const int bk = blockIdx.x / blocksPerK;
  const int chunk = blockIdx.x % blocksPerK;
  const float* kb = kern + bk * 4096;
  for (int idx = threadIdx.x; idx < 4096; idx += 256) {
    int i = idx >> 6, c = idx & 63;
    ldsBT[c * WPAD + i] = (__bf16)kb[idx];
  }
  __syncthreads();
  const int lane = threadIdx.x & 63;
  const int wave = threadIdx.x >> 6;
  const int r = lane & 15, g = lane >> 4;
  bf16x8 bfrag[2][4];
#pragma unroll
  for (int s = 0; s < 2; ++s)
#pragma unroll
    for (int t = 0; t < 4; ++t)
      bfrag[s][t] = *(const bf16x8*)&ldsBT[(t * 16 + r) * WPAD + g * 8 + s * 32];
  const int* ninK = nin + bk * Lpairs;
  const int* noutK = nout + bk * Lpairs;
  const int base0 = chunk * 512 + wave * 128;
  for (int it = 0; it < 8; ++it) {
    const int base = base0 + it * 16;
    if (base >= Lpairs) break;
    const int arow = ninK[base + r];
    const float* ap = feat + (size_t)arow * 64 + g * 8;
    f32x4 f0 = *(const f32x4*)(ap);
    f32x4 f1 = *(const f32x4*)(ap + 4);
    f32x4 f2 = *(const f32x4*)(ap + 32);
    f32x4 f3 = *(const f32x4*)(ap + 36);
    bf16x8 a0, a1;
#pragma unroll
    for (int j = 0; j < 4; ++j) {
      a0[j] = (__bf16)f0[j];
      a0[j + 4] = (__bf16)f1[j];
      a1[j] = (__bf16)f2[j];
      a1[j + 4] = (__bf16)f3[j];
    }
    f32x4 acc[4] = {f32x4{0.f, 0.f, 0.f, 0.f}, f32x4{0.f, 0.f, 0.f, 0.f},
                    f32x4{0.f, 0.f, 0.f, 0.f}, f32x4{0.f, 0.f, 0.f, 0.f}};
#pragma unroll
    for (int t = 0; t < 4; ++t) {
      acc[t] = __builtin_amdgcn_mfma_f32_16x16x32_bf16(a0, bfrag[0][t], acc[t], 0, 0, 0);
      acc[t] = __builtin_amdgcn_mfma_f32_16x16x32_bf16(a1, bfrag[1][t], acc[t], 0, 0, 0);
    }
    int orow[4];
#pragma unroll
    for (int reg = 0; reg < 4; ++reg) orow[reg] = noutK[base + g * 4 + reg];
#pragma unroll
    for (int t = 0; t < 4; ++t)
#pragma unroll
      for (int reg = 0; reg < 4; ++reg)
        atomicAdd(out + (size_t)orow[reg] * 64 + t * 16 + r, acc[t][reg]);
  }
}

extern "C" void kernel_launch(void* const* d_in, const int* in_sizes, int n_in,
                              void* d_out, int out_size, void* d_ws, size_t ws_size,
                              hipStream_t stream) {
  const float* feat = (const float*)d_in[0];
  const float* kern = (const float*)d_in[1];
  const int* nin = (const int*)d_in[2];
  const int* nout = (const int*)d_in[3];
  float* out = (float*)d_out;

  const int total = in_sizes[2];        // 27*L pairs
  const int Lpairs = total / KOFF;      // 50000
  const int Nrows = out_size / 64;      // 100000
  const int nElems = Nrows * 64;

  // ws layout: slots (u16, 0xFF-init) | ovf | ovfcnt | fb (bf16 features)
  const size_t slotsBytes = (size_t)Nrows * NSLOT * 2;
  const size_t ovfOff = (slotsBytes + 255) & ~(size_t)255;
  const size_t cntOff = (ovfOff + (size_t)OVFCAP * 8 + 255) & ~(size_t)255;
  const size_t fbOff = (cntOff + 256 + 255) & ~(size_t)255;
  const size_t needed = fbOff + (size_t)nElems * 2;

  const bool shapeOK = (Lpairs <= 65535) && (Lpairs % 16 == 0) &&
                       (total % KOFF == 0) && (out_size % 64 == 0);

  if (shapeOK && ws_size >= needed) {
    unsigned short* slots = (unsigned short*)d_ws;
    int2* ovf = (int2*)((char*)d_ws + ovfOff);
    int* ovfcnt = (int*)((char*)d_ws + cntOff);
    __bf16* fb = (__bf16*)((char*)d_ws + fbOff);

    hipMemsetAsync(slots, 0xFF, slotsBytes, stream);
    hipMemsetAsync(ovfcnt, 0, 4, stream);

    const int nchunk = (Nrows + ROWCHUNK - 1) / ROWCHUNK;
    const int rankBlocks = KOFF * nchunk;
    const int castBlocks = (nElems / 8 + 255) / 256;
    kA_rank_cast<<<rankBlocks + castBlocks, 256, 0, stream>>>(
        feat, nout, fb, slots, ovf, ovfcnt, Lpairs, nElems, nchunk, rankBlocks);
    kF_fused<<<(Nrows + 63) / 64, 256, 0, stream>>>(fb, kern, nin, slots, out,
                                                    Lpairs, Nrows);
    k4_fixup<<<OVFCAP * 64 / 256, 256, 0, stream>>>(fb, kern, nin, ovf, ovfcnt,
                                                    out, Lpairs);
  } else {
    const int blocksPerK = (Lpairs + 511) / 512;
    hipMemsetAsync(d_out, 0, (size_t)out_size * sizeof(float), stream);
    spconv_atomic_kernel<<<KOFF * blocksPerK, 256, 0, stream>>>(
        feat, kern, nin, nout, out, Lpairs, blocksPerK);
  }
}

// Round 10
// 135.422 us; speedup vs baseline: 1.2543x; 1.1996x over previous
//
#include <hip/hip_runtime.h>
#include <hip/hip_bf16.h>

// Sparse conv for MI355X (gfx950), fused output-stationary design:
//   kA : rank-blocks (LDS nibble counters -> sparse slot table [row][27][4] u16)
//        + wt-blocks (kern f32 -> transposed bf16 wt[k][c][i] table, built once)
//        + cast-blocks (f32 -> bf16 feature table fb)
//   kF : fused kernel. Wave owns 16 output rows; accumulator D[64ch][16rows]
//        in registers across all 27 offsets. Per k: read slot cell, gather+sum
//        features (linearity), 8 MFMAs vs W[k] staged from wt via pure
//        b128 copies into double-buffered LDS. Out written once, no vals.
//   k4 : overflow fixup (~500 pairs) recomputes feat.W directly, atomicAdd.
// Fallback to a pure-atomic kernel for exotic shapes / tiny ws.

typedef __bf16 bf16x8 __attribute__((ext_vector_type(8)));
typedef float f32x4 __attribute__((ext_vector_type(4)));

#define KOFF 27
#define SLOTK 4                 // slots per (row,k) cell
#define NSLOT (KOFF * SLOTK)    // 108 entries per row
#define OVFCAP 8192             // overflow list capacity (E[ovf] ~ 505)
#define WPAD 72                 // LDS pad for W tile (rows 144B, 16B-aligned)
#define ROWCHUNK 8192           // rows per rank-block chunk
#define NIBW (ROWCHUNK / 8)     // 4 KB LDS nibble counters

// ---- kA: chunked rank-builder + W transpose/cast + feature cast ----
__global__ __launch_bounds__(256) void kA_rank_cast(
    const float* __restrict__ feat, const float* __restrict__ kern,
    const int* __restrict__ nout, __bf16* __restrict__ fb,
    __bf16* __restrict__ wt, unsigned short* __restrict__ slots,
    int2* __restrict__ ovf, int* __restrict__ ovfcnt, int Lpairs, int nElems,
    int nchunk, int rankBlocks, int wtBlocks) {
  __shared__ unsigned int nib[NIBW];
  if ((int)blockIdx.x < rankBlocks) {
    const int k = blockIdx.x / nchunk;
    const int chunk = blockIdx.x % nchunk;
    const int lo = chunk * ROWCHUNK;
    const int tid = threadIdx.x;
    for (int i = tid; i < NIBW; i += 256) nib[i] = 0u;
    __syncthreads();
    const int* nk = nout + k * Lpairs;
    for (int base = 0; base < Lpairs; base += 2048) {
      int l[8], row[8];
#pragma unroll
      for (int j = 0; j < 8; ++j) {
        l[j] = base + j * 256 + tid;
        row[j] = (l[j] < Lpairs) ? nk[l[j]] : -1;
      }
#pragma unroll
      for (int j = 0; j < 8; ++j) {
        int rr = row[j] - lo;
        if (rr >= 0 && rr < ROWCHUNK) {
          unsigned int sh = ((unsigned)rr & 7u) * 4u;
          unsigned int old = atomicAdd(&nib[rr >> 3], 1u << sh);
          int rank = (old >> sh) & 15;
          if (rank < SLOTK) {
            slots[(size_t)row[j] * NSLOT + k * SLOTK + rank] =
                (unsigned short)l[j];
          } else {
            int idx = atomicAdd(ovfcnt, 1);
            if (idx < OVFCAP) ovf[idx] = make_int2(row[j], k * Lpairs + l[j]);
          }
        }
      }
    }
  } else if ((int)blockIdx.x < rankBlocks + wtBlocks) {
    // W transpose/cast: wt[k][c*64+i] = (bf16)kern[k*4096 + i*64 + c]
    int kc = (blockIdx.x - rankBlocks) * 256 + threadIdx.x;
    if (kc < KOFF * 64) {
      int k = kc >> 6, c = kc & 63;
      const float* src = kern + k * 4096 + c;
      __bf16* dst = wt + (size_t)kc * 64;
#pragma unroll
      for (int i0 = 0; i0 < 64; i0 += 8) {
        bf16x8 v;
#pragma unroll
        for (int q = 0; q < 8; ++q) v[q] = (__bf16)src[(i0 + q) * 64];
        *(bf16x8*)(dst + i0) = v;
      }
    }
  } else {
    int i = ((blockIdx.x - rankBlocks - wtBlocks) * 256 + threadIdx.x) * 8;
    if (i < nElems) {
      f32x4 a = *(const f32x4*)(feat + i);
      f32x4 b = *(const f32x4*)(feat + i + 4);
      bf16x8 v;
#pragma unroll
      for (int j = 0; j < 4; ++j) {
        v[j] = (__bf16)a[j];
        v[j + 4] = (__bf16)b[j];
      }
      *(bf16x8*)(fb + i) = v;
    }
  }
}

// ---- kF: fused output-stationary GEMM ----
// Wave handles rows rowbase..rowbase+15. Lane (g = lane>>4, r = lane&15):
//   B operand per k: summed cell features of row (rowbase+r)
//   A operand: W[k]^T fragments from LDS (staged from wt via b128 copies)
//   D: col=r -> row, row=g*4+reg (+t*16) -> channel; held in regs across k.
__global__ __launch_bounds__(256) void kF_fused(
    const __bf16* __restrict__ fb, const __bf16* __restrict__ wt,
    const int* __restrict__ nin, const unsigned short* __restrict__ slots,
    float* __restrict__ out, int Lpairs, int Nrows) {
  __shared__ __bf16 ldsW[2][64 * WPAD];
  const int tid = threadIdx.x;
  const int wv = tid >> 6, lane = tid & 63;
  const int r = lane & 15, g = lane >> 4;
  int row = blockIdx.x * 64 + wv * 16 + r;
  if (row >= Nrows) row = Nrows - 1;  // duplicate rows write identical values
  const unsigned short* srow = slots + (size_t)row * NSLOT;

  // staging coords: thread copies W row c = tid>>2, elems [si, si+16)
  const int sc = tid >> 2;
  const int si = (tid & 3) * 16;

  // stage W[0]: pure vector copy (2 x 16B load, 2 x ds_write_b128)
  {
    const __bf16* wp = wt + sc * 64 + si;
    bf16x8 wa = *(const bf16x8*)(wp);
    bf16x8 wb = *(const bf16x8*)(wp + 8);
    *(bf16x8*)&ldsW[0][sc * WPAD + si] = wa;
    *(bf16x8*)&ldsW[0][sc * WPAD + si + 8] = wb;
  }

  // Index pipeline prologue: slot entries for k=0,1; nin rows for k=0.
  uint2 sv0 = *(const uint2*)(srow);
  uint2 sv1 = *(const uint2*)(srow + SLOTK);
  int e[4] = {(int)(sv0.x & 0xFFFF), (int)(sv0.x >> 16),
              (int)(sv0.y & 0xFFFF), (int)(sv0.y >> 16)};
  int en[4] = {(int)(sv1.x & 0xFFFF), (int)(sv1.x >> 16),
               (int)(sv1.y & 0xFFFF), (int)(sv1.y >> 16)};
  int irow[4], irown[4];
#pragma unroll
  for (int j = 0; j < 4; ++j) irow[j] = (e[j] != 0xFFFF) ? nin[e[j]] : -1;

  f32x4 acc[4] = {f32x4{0.f, 0.f, 0.f, 0.f}, f32x4{0.f, 0.f, 0.f, 0.f},
                  f32x4{0.f, 0.f, 0.f, 0.f}, f32x4{0.f, 0.f, 0.f, 0.f}};
  __syncthreads();

  for (int k = 0; k < KOFF; ++k) {
    const int kb = k & 1;
    // (1) gather loads for k (indices ready) -- up to 8 independent 16B loads
    bf16x8 fa[4], fc[4];
#pragma unroll
    for (int j = 0; j < 4; ++j) {
      if (irow[j] >= 0) {
        const __bf16* ap = fb + (size_t)irow[j] * 64 + g * 8;
        fa[j] = *(const bf16x8*)(ap);
        fc[j] = *(const bf16x8*)(ap + 32);
      }
    }
    // (2) nin loads for k+1 (entries ready)
    const int* ninK1 = nin + (k + 1) * Lpairs;
#pragma unroll
    for (int j = 0; j < 4; ++j)
      irown[j] = (k + 1 < KOFF && en[j] != 0xFFFF) ? ninK1[en[j]] : -1;
    // (3) slot entries for k+2
    uint2 sv2 = make_uint2(0xFFFFFFFFu, 0xFFFFFFFFu);
    if (k + 2 < KOFF) sv2 = *(const uint2*)(srow + (k + 2) * SLOTK);
    // (4) stage W[k+1] into the other LDS buffer (pure b128 copies)
    if (k + 1 < KOFF) {
      const __bf16* wp = wt + (size_t)(k + 1) * 4096 + sc * 64 + si;
      bf16x8 wa = *(const bf16x8*)(wp);
      bf16x8 wb = *(const bf16x8*)(wp + 8);
      *(bf16x8*)&ldsW[kb ^ 1][sc * WPAD + si] = wa;
      *(bf16x8*)&ldsW[kb ^ 1][sc * WPAD + si + 8] = wb;
    }
    // (5) cell pre-sum in f32 (linearity: sum before GEMM)
    float s0[8] = {0.f, 0.f, 0.f, 0.f, 0.f, 0.f, 0.f, 0.f};
    float s1[8] = {0.f, 0.f, 0.f, 0.f, 0.f, 0.f, 0.f, 0.f};
#pragma unroll
    for (int j = 0; j < 4; ++j) {
      if (irow[j] >= 0) {
#pragma unroll
        for (int q = 0; q < 8; ++q) {
          s0[q] += (float)fa[j][q];
          s1[q] += (float)fc[j][q];
        }
      }
    }
    bf16x8 b0, b1;
#pragma unroll
    for (int q = 0; q < 8; ++q) {
      b0[q] = (__bf16)s0[q];
      b1[q] = (__bf16)s1[q];
    }
    // (6) W fragments from LDS + 8 MFMAs accumulating into persistent acc
    bf16x8 w0f[4], w1f[4];
#pragma unroll
    for (int t = 0; t < 4; ++t) {
      w0f[t] = *(const bf16x8*)&ldsW[kb][(t * 16 + r) * WPAD + g * 8];
      w1f[t] = *(const bf16x8*)&ldsW[kb][(t * 16 + r) * WPAD + g * 8 + 32];
    }
#pragma unroll
    for (int t = 0; t < 4; ++t) {
      acc[t] = __builtin_amdgcn_mfma_f32_16x16x32_bf16(w0f[t], b0, acc[t], 0, 0, 0);
      acc[t] = __builtin_amdgcn_mfma_f32_16x16x32_bf16(w1f[t], b1, acc[t], 0, 0, 0);
    }
    __syncthreads();
    // rotate index pipeline
#pragma unroll
    for (int j = 0; j < 4; ++j) irow[j] = irown[j];
    en[0] = (int)(sv2.x & 0xFFFF);
    en[1] = (int)(sv2.x >> 16);
    en[2] = (int)(sv2.y & 0xFFFF);
    en[3] = (int)(sv2.y >> 16);
  }

  // Epilogue: lane (g,r) holds channels t*16+g*4+{0..3} of row.
  float* op = out + (size_t)row * 64;
#pragma unroll
  for (int t = 0; t < 4; ++t) *(f32x4*)(op + t * 16 + g * 4) = acc[t];
}

// ---- k4: overflow fixup (~500 pairs): recompute feat.W (bf16), atomicAdd ----
__global__ __launch_bounds__(256) void k4_fixup(
    const __bf16* __restrict__ fb, const __bf16* __restrict__ wt,
    const int* __restrict__ nin, const int2* __restrict__ ovf,
    const int* __restrict__ ovfcnt, float* __restrict__ out, int Lpairs) {
  int gid = blockIdx.x * 256 + threadIdx.x;
  int i = gid >> 6, c = gid & 63;
  int n = *ovfcnt;
  if (n > OVFCAP) n = OVFCAP;
  if (i >= n) return;
  int row = ovf[i].x, pid = ovf[i].y;
  int k = pid / Lpairs;
  int irow = nin[pid];
  const __bf16* wk = wt + ((size_t)k * 64 + c) * 64;  // wt[k][c][*]
  const __bf16* f = fb + (size_t)irow * 64;
  float s = 0.f;
#pragma unroll 8
  for (int q = 0; q < 64; ++q) s += (float)f[q] * (float)wk[q];
  atomicAdd(&out[(size_t)row * 64 + c], s);
}

// ---- Fallback: atomic kernel (exotic shapes / tiny ws) ----
__global__ __launch_bounds__(256) void spconv_atomic_kernel(
    const float* __restrict__ feat, const float* __restrict__ kern,
    const int* __restrict__ nin, const int* __restrict__ nout,
    float* __restrict__ out, int Lpairs, int blocksPerK) {
  __shared__ __bf16 ldsBT[64 * WPAD];
  const int bk = blockIdx.x / blocksPerK;
  const int chunk = blockIdx.x % blocksPerK;
  const float* kb = kern + bk * 4096;
  for (int idx = threadIdx.x; idx < 4096; idx += 256) {
    int i = idx >> 6, c = idx & 63;
    ldsBT[c * WPAD + i] = (__bf16)kb[idx];
  }
  __syncthreads();
  const int lane = threadIdx.x & 63;
  const int wave = threadIdx.x >> 6;
  const int r = lane & 15, g = lane >> 4;
  bf16x8 bfrag[2][4];
#pragma unroll
  for (int s = 0; s < 2; ++s)
#pragma unroll
    for (int t = 0; t < 4; ++t)
      bfrag[s][t] = *(const bf16x8*)&ldsBT[(t * 16 + r) * WPAD + g * 8 + s * 32];
  const int* ninK = nin + bk * Lpairs;
  const int* noutK = nout + bk * Lpairs;
  const int base0 = chunk * 512 + wave * 128;
  for (int it = 0; it < 8; ++it) {
    const int base = base0 + it * 16;
    if (base >= Lpairs) break;
    const int arow = ninK[base + r];
    const float* ap = feat + (size_t)arow * 64 + g * 8;
    f32x4 f0 = *(const f32x4*)(ap);
    f32x4 f1 = *(const f32x4*)(ap + 4);
    f32x4 f2 = *(const f32x4*)(ap + 32);
    f32x4 f3 = *(const f32x4*)(ap + 36);
    bf16x8 a0, a1;
#pragma unroll
    for (int j = 0; j < 4; ++j) {
      a0[j] = (__bf16)f0[j];
      a0[j + 4] = (__bf16)f1[j];
      a1[j] = (__bf16)f2[j];
      a1[j + 4] = (__bf16)f3[j];
    }
    f32x4 acc[4] = {f32x4{0.f, 0.f, 0.f, 0.f}, f32x4{0.f, 0.f, 0.f, 0.f},
                    f32x4{0.f, 0.f, 0.f, 0.f}, f32x4{0.f, 0.f, 0.f, 0.f}};
#pragma unroll
    for (int t = 0; t < 4; ++t) {
      acc[t] = __builtin_amdgcn_mfma_f32_16x16x32_bf16(a0, bfrag[0][t], acc[t], 0, 0, 0);
      acc[t] = __builtin_amdgcn_mfma_f32_16x16x32_bf16(a1, bfrag[1][t], acc[t], 0, 0, 0);
    }
    int orow[4];
#pragma unroll
    for (int reg = 0; reg < 4; ++reg) orow[reg] = noutK[base + g * 4 + reg];
#pragma unroll
    for (int t = 0; t < 4; ++t)
#pragma unroll
      for (int reg = 0; reg < 4; ++reg)
        atomicAdd(out + (size_t)orow[reg] * 64 + t * 16 + r, acc[t][reg]);
  }
}

extern "C" void kernel_launch(void* const* d_in, const int* in_sizes, int n_in,
                              void* d_out, int out_size, void* d_ws, size_t ws_size,
                              hipStream_t stream) {
  const float* feat = (const float*)d_in[0];
  const float* kern = (const float*)d_in[1];
  const int* nin = (const int*)d_in[2];
  const int* nout = (const int*)d_in[3];
  float* out = (float*)d_out;

  const int total = in_sizes[2];        // 27*L pairs
  const int Lpairs = total / KOFF;      // 50000
  const int Nrows = out_size / 64;      // 100000
  const int nElems = Nrows * 64;

  // ws layout: slots (u16, 0xFF-init) | ovf | ovfcnt | wt (bf16 W^T) | fb
  const size_t slotsBytes = (size_t)Nrows * NSLOT * 2;
  const size_t ovfOff = (slotsBytes + 255) & ~(size_t)255;
  const size_t cntOff = (ovfOff + (size_t)OVFCAP * 8 + 255) & ~(size_t)255;
  const size_t wtOff = (cntOff + 256 + 255) & ~(size_t)255;
  const size_t fbOff = (wtOff + (size_t)KOFF * 4096 * 2 + 255) & ~(size_t)255;
  const size_t needed = fbOff + (size_t)nElems * 2;

  const bool shapeOK = (Lpairs <= 65535) && (Lpairs % 16 == 0) &&
                       (total % KOFF == 0) && (out_size % 64 == 0);

  if (shapeOK && ws_size >= needed) {
    unsigned short* slots = (unsigned short*)d_ws;
    int2* ovf = (int2*)((char*)d_ws + ovfOff);
    int* ovfcnt = (int*)((char*)d_ws + cntOff);
    __bf16* wt = (__bf16*)((char*)d_ws + wtOff);
    __bf16* fb = (__bf16*)((char*)d_ws + fbOff);

    hipMemsetAsync(slots, 0xFF, slotsBytes, stream);
    hipMemsetAsync(ovfcnt, 0, 4, stream);

    const int nchunk = (Nrows + ROWCHUNK - 1) / ROWCHUNK;
    const int rankBlocks = KOFF * nchunk;
    const int wtBlocks = (KOFF * 64 + 255) / 256;  // 7
    const int castBlocks = (nElems / 8 + 255) / 256;
    kA_rank_cast<<<rankBlocks + wtBlocks + castBlocks, 256, 0, stream>>>(
        feat, kern, nout, fb, wt, slots, ovf, ovfcnt, Lpairs, nElems, nchunk,
        rankBlocks, wtBlocks);
    kF_fused<<<(Nrows + 63) / 64, 256, 0, stream>>>(fb, wt, nin, slots, out,
                                                    Lpairs, Nrows);
    k4_fixup<<<OVFCAP * 64 / 256, 256, 0, stream>>>(fb, wt, nin, ovf, ovfcnt,
                                                    out, Lpairs);
  } else {
    const int blocksPerK = (Lpairs + 511) / 512;
    hipMemsetAsync(d_out, 0, (size_t)out_size * sizeof(float), stream);
    spconv_atomic_kernel<<<KOFF * blocksPerK, 256, 0, stream>>>(
        feat, kern, nin, nout, out, Lpairs, blocksPerK);
  }
}